// Round 3
// baseline (30732.700 us; speedup 1.0000x reference)
//
#include <hip/hip_runtime.h>

typedef __attribute__((ext_vector_type(8))) short short8;
typedef __attribute__((ext_vector_type(4))) short short4e;
typedef __attribute__((ext_vector_type(4))) float f32x4;

#define DT (1.0f/256.0f)
#define NSTEPS 256

__device__ __forceinline__ short f2bf(float f) {
    unsigned u = __float_as_uint(f);
    u = (u + 0x7fffu + ((u >> 16) & 1u)) >> 16;
    return (short)u;
}

__device__ __forceinline__ float fast_tanh(float x) {
    float e = __expf(2.f * x);
    return 1.f - __fdividef(2.f, e + 1.f);
}

// agent-scope (device-coherent, cache-bypassing) accesses for cross-XCD data
__device__ __forceinline__ float ld_agent(const float* p) {
    return __hip_atomic_load(p, __ATOMIC_RELAXED, __HIP_MEMORY_SCOPE_AGENT);
}
__device__ __forceinline__ void st_agent(float* p, float v) {
    __hip_atomic_store(p, v, __ATOMIC_RELAXED, __HIP_MEMORY_SCOPE_AGENT);
}

// ---------------- weight permutation (A-fragment order, bf16) ----------------
__global__ void perm_w0(const float* __restrict__ W0, short* __restrict__ W0p) {
    int i = blockIdx.x * 256 + threadIdx.x;            // 32768 = 16ot*4kc*64*8
    int j = i & 7, l = (i >> 3) & 63, kc = (i >> 9) & 3, ot = i >> 11;
    int row = ot * 16 + (l & 15);
    int col = kc * 32 + ((l >> 4) << 3) + j;
    W0p[i] = f2bf(W0[row * 128 + col]);
}
__global__ void perm_w1(const float* __restrict__ W1, short* __restrict__ W1p) {
    int i = blockIdx.x * 256 + threadIdx.x;            // 131072 = 16ot*8kc*64*8
    int j = i & 7, l = (i >> 3) & 63, kc = (i >> 9) & 7, ot = i >> 12;
    int row = ot * 16 + (l & 15);
    int col = kc * 32 + ((l >> 4) << 3) + j;
    W1p[i] = f2bf(W1[row * 256 + col]);
}
// padded: 64 lv rows per h-tile (row 63 zeroed)
__global__ void perm_w2(const float* __restrict__ W2, short* __restrict__ W2p) {
    int i = blockIdx.x * 256 + threadIdx.x;            // 2097152 = 8ht*64lv*8kc*64*8
    int j = i & 7, ln = (i >> 3) & 63, kc = (i >> 9) & 7;
    int v = i >> 12;                                   // ht*64 + lv
    int ht = v >> 6, lv = v & 63;
    if (lv == 63) { W2p[i] = 0; return; }
    int row = (ht * 16 + (ln & 15)) * 63 + lv;         // W2 row = h*63 + l
    int col = kc * 32 + ((ln >> 4) << 3) + j;
    W2p[i] = f2bf(W2[row * 256 + col]);
}

// ---------------- y0 = x0 @ l1w^T + l1b ----------------
__global__ void y0_kernel(const float* __restrict__ x0, const float* __restrict__ l1w,
                          const float* __restrict__ l1b, float* __restrict__ y) {
    int i = blockIdx.x * 256 + threadIdx.x;            // 65536
    int b = i >> 7, h = i & 127;
    float s = l1b[h];
    #pragma unroll
    for (int d = 0; d < 8; ++d) s += x0[b * 8 + d] * l1w[h * 8 + d];
    y[i] = s;
}

// ---------------- persistent RK integrator ----------------
struct Smem {
    alignas(16) short ysb[16 * 136];
    alignas(16) short h1b[16 * 264];
    alignas(16) short h2b[16 * 264];
    float gsh[16 * 65];
    float b2sh[16 * 65];
    float b0sh[256];
    float b1sh[256];
    float kred[8][16][17];
};

template<int STAGE>
__device__ __forceinline__ void do_stage(
    Smem& sm, int s, int bg, int ht, int tid,
    const float* __restrict__ ycur, float* __restrict__ ynext,
    float* __restrict__ kbuf,
    const short* __restrict__ W0p, const short* __restrict__ W1p, const short* __restrict__ W2p,
    const float* __restrict__ logsig,
    unsigned* __restrict__ barctr, int phase)
{
    const int w    = tid >> 6;
    const int lane = tid & 63;
    const int q    = lane >> 4;
    const int rr   = lane & 15;

    // ---------- phase 0: stage combo -> ysb (bf16); g refresh at stage 2 ----------
    {
        const int r  = tid >> 5;            // 0..15
        const int c4 = (tid & 31) * 4;      // 0..124
        const float* yrow = ycur + (bg * 16 + r) * 128 + c4;
        float v[4];
        #pragma unroll
        for (int ii = 0; ii < 4; ++ii) v[ii] = ld_agent(yrow + ii);
        if constexpr (STAGE >= 2) {
            constexpr float cf[5][5] = {
                {0.161f, 0.f, 0.f, 0.f, 0.f},
                {-0.008480655492356989f, 0.335480655492357f, 0.f, 0.f, 0.f},
                {2.8971530571054935f, -6.359448489975075f, 4.3622954328695815f, 0.f, 0.f},
                {5.325864828439257f, -11.748883564062828f, 7.4955393428898365f, -0.09249506636175525f, 0.f},
                {5.86145544294642f, -12.92096931784711f, 8.159367898576159f, -0.071584973281401f, -0.028269050394068383f}};
            #pragma unroll
            for (int kk = 0; kk < STAGE - 1; ++kk) {
                const float c = DT * cf[STAGE - 2][kk];
                const float* kr = kbuf + kk * 65536 + (bg * 16 + r) * 128 + c4;
                #pragma unroll
                for (int ii = 0; ii < 4; ++ii) v[ii] += c * ld_agent(kr + ii);
            }
        }
        short4e sv;
        #pragma unroll
        for (int ii = 0; ii < 4; ++ii) sv[ii] = f2bf(v[ii]);
        *reinterpret_cast<short4e*>(&sm.ysb[r * 136 + c4]) = sv;

        if constexpr (STAGE == 2) {         // refresh g for idx = s (used by stages 2..6 and stage 1 of step s+1)
            const int l0 = (tid & 31) * 2;
            const float* gp = logsig + (bg * 16 + r) * 16384 + s * 64 + 1;
            sm.gsh[r * 65 + l0]     = (l0 < 63)     ? gp[l0]     : 0.f;
            sm.gsh[r * 65 + l0 + 1] = (l0 + 1 < 63) ? gp[l0 + 1] : 0.f;
        }
    }
    __syncthreads();

    // ---------- phase 1: h1 = silu(W0 @ ys^T + b0) ----------
    #pragma unroll
    for (int oi = 0; oi < 2; ++oi) {
        int ot = w * 2 + oi;
        f32x4 acc0 = {0.f, 0.f, 0.f, 0.f}, acc1 = {0.f, 0.f, 0.f, 0.f};
        #pragma unroll
        for (int kc = 0; kc < 2; ++kc) {
            short8 af0 = *reinterpret_cast<const short8*>(W0p + (ot * 4 + kc) * 512 + lane * 8);
            short8 bf0 = *reinterpret_cast<const short8*>(&sm.ysb[rr * 136 + kc * 32 + q * 8]);
            acc0 = __builtin_amdgcn_mfma_f32_16x16x32_bf16(af0, bf0, acc0, 0, 0, 0);
            short8 af1 = *reinterpret_cast<const short8*>(W0p + (ot * 4 + kc + 2) * 512 + lane * 8);
            short8 bf1 = *reinterpret_cast<const short8*>(&sm.ysb[rr * 136 + (kc + 2) * 32 + q * 8]);
            acc1 = __builtin_amdgcn_mfma_f32_16x16x32_bf16(af1, bf1, acc1, 0, 0, 0);
        }
        int ob = ot * 16 + q * 4;
        float vv[4];
        #pragma unroll
        for (int jj = 0; jj < 4; ++jj) {
            float x = acc0[jj] + acc1[jj] + sm.b0sh[ob + jj];
            vv[jj] = x * __fdividef(1.f, 1.f + __expf(-x));
        }
        unsigned lo = (unsigned)(unsigned short)f2bf(vv[0]) | ((unsigned)(unsigned short)f2bf(vv[1]) << 16);
        unsigned hi = (unsigned)(unsigned short)f2bf(vv[2]) | ((unsigned)(unsigned short)f2bf(vv[3]) << 16);
        *reinterpret_cast<unsigned*>(&sm.h1b[rr * 264 + ob])     = lo;
        *reinterpret_cast<unsigned*>(&sm.h1b[rr * 264 + ob + 2]) = hi;
    }
    __syncthreads();

    // ---------- phase 2: h2 = silu(W1 @ h1^T + b1) ----------
    #pragma unroll
    for (int oi = 0; oi < 2; ++oi) {
        int ot = w * 2 + oi;
        f32x4 acc0 = {0.f, 0.f, 0.f, 0.f}, acc1 = {0.f, 0.f, 0.f, 0.f};
        #pragma unroll
        for (int kc = 0; kc < 4; ++kc) {
            short8 af0 = *reinterpret_cast<const short8*>(W1p + (ot * 8 + kc) * 512 + lane * 8);
            short8 bf0 = *reinterpret_cast<const short8*>(&sm.h1b[rr * 264 + kc * 32 + q * 8]);
            acc0 = __builtin_amdgcn_mfma_f32_16x16x32_bf16(af0, bf0, acc0, 0, 0, 0);
            short8 af1 = *reinterpret_cast<const short8*>(W1p + (ot * 8 + kc + 4) * 512 + lane * 8);
            short8 bf1 = *reinterpret_cast<const short8*>(&sm.h1b[rr * 264 + (kc + 4) * 32 + q * 8]);
            acc1 = __builtin_amdgcn_mfma_f32_16x16x32_bf16(af1, bf1, acc1, 0, 0, 0);
        }
        int ob = ot * 16 + q * 4;
        float vv[4];
        #pragma unroll
        for (int jj = 0; jj < 4; ++jj) {
            float x = acc0[jj] + acc1[jj] + sm.b1sh[ob + jj];
            vv[jj] = x * __fdividef(1.f, 1.f + __expf(-x));
        }
        unsigned lo = (unsigned)(unsigned short)f2bf(vv[0]) | ((unsigned)(unsigned short)f2bf(vv[1]) << 16);
        unsigned hi = (unsigned)(unsigned short)f2bf(vv[2]) | ((unsigned)(unsigned short)f2bf(vv[3]) << 16);
        *reinterpret_cast<unsigned*>(&sm.h2b[rr * 264 + ob])     = lo;
        *reinterpret_cast<unsigned*>(&sm.h2b[rr * 264 + ob + 2]) = hi;
    }
    __syncthreads();

    // ---------- phase 3: k_slice[b][h] = sum_l tanh(W2[h*63+l]·h2[b] + b2) * g[b][l] ----------
    float kacc[4] = {0.f, 0.f, 0.f, 0.f};
    const int lvbase = w * 8;
    #pragma unroll
    for (int i2 = 0; i2 < 4; ++i2) {
        const int lvA = lvbase + i2 * 2;
        const int lvB = lvA + 1;
        f32x4 aA0 = {0.f,0.f,0.f,0.f}, aA1 = {0.f,0.f,0.f,0.f};
        f32x4 aB0 = {0.f,0.f,0.f,0.f}, aB1 = {0.f,0.f,0.f,0.f};
        const short* wpA = W2p + (size_t)((ht * 64 + lvA) * 8) * 512 + lane * 8;
        const short* wpB = wpA + 8 * 512;
        #pragma unroll
        for (int kc = 0; kc < 4; ++kc) {
            short8 bf0 = *reinterpret_cast<const short8*>(&sm.h2b[rr * 264 + kc * 32 + q * 8]);
            short8 bf1 = *reinterpret_cast<const short8*>(&sm.h2b[rr * 264 + (kc + 4) * 32 + q * 8]);
            aA0 = __builtin_amdgcn_mfma_f32_16x16x32_bf16(*reinterpret_cast<const short8*>(wpA + kc * 512),       bf0, aA0, 0, 0, 0);
            aA1 = __builtin_amdgcn_mfma_f32_16x16x32_bf16(*reinterpret_cast<const short8*>(wpA + (kc + 4) * 512), bf1, aA1, 0, 0, 0);
            aB0 = __builtin_amdgcn_mfma_f32_16x16x32_bf16(*reinterpret_cast<const short8*>(wpB + kc * 512),       bf0, aB0, 0, 0, 0);
            aB1 = __builtin_amdgcn_mfma_f32_16x16x32_bf16(*reinterpret_cast<const short8*>(wpB + (kc + 4) * 512), bf1, aB1, 0, 0, 0);
        }
        float gA = sm.gsh[rr * 65 + lvA];
        float gB = sm.gsh[rr * 65 + lvB];
        #pragma unroll
        for (int jj = 0; jj < 4; ++jj) {
            float xA = aA0[jj] + aA1[jj] + sm.b2sh[(q * 4 + jj) * 65 + lvA];
            kacc[jj] += fast_tanh(xA) * gA;
            float xB = aB0[jj] + aB1[jj] + sm.b2sh[(q * 4 + jj) * 65 + lvB];
            kacc[jj] += fast_tanh(xB) * gB;
        }
    }
    #pragma unroll
    for (int jj = 0; jj < 4; ++jj) sm.kred[w][q * 4 + jj][rr] = kacc[jj];
    __syncthreads();

    // ---------- epilogue: cross-wave reduce, publish k (or y_new for stage 6) ----------
    if (tid < 256) {
        int bl = tid >> 4;
        int hl = tid & 15;
        float ssum = sm.kred[0][hl][bl] + sm.kred[1][hl][bl] + sm.kred[2][hl][bl] + sm.kred[3][hl][bl]
                   + sm.kred[4][hl][bl] + sm.kred[5][hl][bl] + sm.kred[6][hl][bl] + sm.kred[7][hl][bl];
        int gi = (bg * 16 + bl) * 128 + ht * 16 + hl;
        if constexpr (STAGE < 6) {
            st_agent(&kbuf[(STAGE - 1) * 65536 + gi], ssum);
        } else {
            float k1v = ld_agent(&kbuf[0 * 65536 + gi]), k2v = ld_agent(&kbuf[1 * 65536 + gi]),
                  k3v = ld_agent(&kbuf[2 * 65536 + gi]), k4v = ld_agent(&kbuf[3 * 65536 + gi]),
                  k5v = ld_agent(&kbuf[4 * 65536 + gi]);
            float yv = ld_agent(&ycur[gi]);
            st_agent(&ynext[gi], yv + DT * (0.09646076681806523f * k1v + 0.01f * k2v
                        + 0.4798896504144996f * k3v + 1.379008574103742f * k4v
                        + (-3.290069515436081f) * k5v + 2.324710524099774f * ssum));
        }
    }

    // ---------- per-bg 8-WG barrier (monotone counter; __syncthreads drains vmcnt first) ----------
    __syncthreads();
    if (tid == 0) {
        __hip_atomic_fetch_add(&barctr[bg * 16], 1u, __ATOMIC_RELEASE, __HIP_MEMORY_SCOPE_AGENT);
        const unsigned target = 8u * (unsigned)phase;
        while (__hip_atomic_load(&barctr[bg * 16], __ATOMIC_ACQUIRE, __HIP_MEMORY_SCOPE_AGENT) < target) { }
    }
    __syncthreads();
}

__global__ __launch_bounds__(512, 2) void rde_persistent(
    float* yb0, float* yb1, float* kbuf, unsigned* barctr,
    const short* W0p, const short* W1p, const short* W2p,
    const float* b0, const float* b1, const float* b2,
    const float* logsig)
{
    __shared__ Smem sm;
    const int tid = threadIdx.x;
    const int bg  = blockIdx.x >> 3;
    const int ht  = blockIdx.x & 7;

    // ---- one-time LDS init: biases + b2 slice + g(idx=0) ----
    if (tid < 256) sm.b0sh[tid] = b0[tid];
    else           sm.b1sh[tid - 256] = b1[tid - 256];
    {
        const int r  = tid >> 5;
        const int l0 = (tid & 31) * 2;
        const float* bp = b2 + (ht * 16 + r) * 63;
        sm.b2sh[r * 65 + l0]     = (l0 < 63)     ? bp[l0]     : 0.f;
        sm.b2sh[r * 65 + l0 + 1] = (l0 + 1 < 63) ? bp[l0 + 1] : 0.f;
        const float* gp = logsig + (bg * 16 + r) * 16384 + 0 * 64 + 1;
        sm.gsh[r * 65 + l0]      = (l0 < 63)     ? gp[l0]     : 0.f;
        sm.gsh[r * 65 + l0 + 1]  = (l0 + 1 < 63) ? gp[l0 + 1] : 0.f;
    }
    // (first __syncthreads inside do_stage<1> covers this init)

    int phase = 1;
    #pragma unroll 1
    for (int s = 0; s < NSTEPS; ++s) {
        const float* yc = (s & 1) ? yb1 : yb0;
        float*       yn = (s & 1) ? yb0 : yb1;
        do_stage<1>(sm, s, bg, ht, tid, yc, nullptr, kbuf, W0p, W1p, W2p, logsig, barctr, phase); ++phase;
        do_stage<2>(sm, s, bg, ht, tid, yc, nullptr, kbuf, W0p, W1p, W2p, logsig, barctr, phase); ++phase;
        do_stage<3>(sm, s, bg, ht, tid, yc, nullptr, kbuf, W0p, W1p, W2p, logsig, barctr, phase); ++phase;
        do_stage<4>(sm, s, bg, ht, tid, yc, nullptr, kbuf, W0p, W1p, W2p, logsig, barctr, phase); ++phase;
        do_stage<5>(sm, s, bg, ht, tid, yc, nullptr, kbuf, W0p, W1p, W2p, logsig, barctr, phase); ++phase;
        do_stage<6>(sm, s, bg, ht, tid, yc, yn,      kbuf, W0p, W1p, W2p, logsig, barctr, phase); ++phase;
    }
}

// ---------------- final: softmax(yf @ l2w^T + l2b) ----------------
__global__ void out_kernel(const float* __restrict__ yf, const float* __restrict__ l2w,
                           const float* __restrict__ l2b, float* __restrict__ out) {
    int b = blockIdx.x, t = threadIdx.x;   // 64 threads
    float ya = yf[b * 128 + t], yb = yf[b * 128 + 64 + t];
    __shared__ float lg[10];
    for (int c = 0; c < 10; ++c) {
        float p = ya * l2w[c * 128 + t] + yb * l2w[c * 128 + 64 + t];
        for (int off = 32; off > 0; off >>= 1) p += __shfl_down(p, off);
        if (t == 0) lg[c] = p + l2b[c];
    }
    __syncthreads();
    if (t == 0) {
        float m = lg[0];
        for (int c = 1; c < 10; ++c) m = fmaxf(m, lg[c]);
        float s = 0.f, e[10];
        for (int c = 0; c < 10; ++c) { e[c] = expf(lg[c] - m); s += e[c]; }
        for (int c = 0; c < 10; ++c) out[b * 10 + c] = e[c] / s;
    }
}

extern "C" void kernel_launch(void* const* d_in, const int* in_sizes, int n_in,
                              void* d_out, int out_size, void* d_ws, size_t ws_size,
                              hipStream_t stream) {
    const float* logsig = (const float*)d_in[2];
    const float* x0  = (const float*)d_in[3];
    const float* W0  = (const float*)d_in[4];
    const float* b0  = (const float*)d_in[5];
    const float* W1  = (const float*)d_in[6];
    const float* b1  = (const float*)d_in[7];
    const float* W2  = (const float*)d_in[8];
    const float* b2  = (const float*)d_in[9];
    const float* l1w = (const float*)d_in[10];
    const float* l1b = (const float*)d_in[11];
    const float* l2w = (const float*)d_in[12];
    const float* l2b = (const float*)d_in[13];
    float* out = (float*)d_out;

    char* ws = (char*)d_ws;
    float*    yb0    = (float*)(ws);                   // 512x128 f32
    float*    yb1    = (float*)(ws + 262144);
    float*    kbuf   = (float*)(ws + 524288);          // 6 x 512x128 f32
    short*    W0p    = (short*)(ws + 2097152);         // 64 KB bf16
    short*    W1p    = (short*)(ws + 2162688);         // 256 KB
    short*    W2p    = (short*)(ws + 2424832);         // 4 MB (padded 8*64*8*512)
    unsigned* barctr = (unsigned*)(ws + 6619136);      // 32 bg x 16 uints (64B padded)

    hipMemsetAsync(barctr, 0, 32 * 16 * sizeof(unsigned), stream);
    perm_w0<<<128, 256, 0, stream>>>(W0, W0p);
    perm_w1<<<512, 256, 0, stream>>>(W1, W1p);
    perm_w2<<<8192, 256, 0, stream>>>(W2, W2p);
    y0_kernel<<<256, 256, 0, stream>>>(x0, l1w, l1b, yb0);

    void* args[] = {&yb0, &yb1, &kbuf, &barctr, &W0p, &W1p, &W2p, &b0, &b1, &b2, &logsig};
    hipLaunchCooperativeKernel((const void*)rde_persistent, dim3(256), dim3(512), args, 0, stream);

    out_kernel<<<512, 64, 0, stream>>>(yb0, l2w, l2b, out);
}

// Round 4
// 20534.451 us; speedup vs baseline: 1.4966x; 1.4966x over previous
//
#include <hip/hip_runtime.h>

typedef __attribute__((ext_vector_type(8))) short short8;
typedef __attribute__((ext_vector_type(4))) short short4e;
typedef __attribute__((ext_vector_type(4))) float f32x4;

#define DT (1.0f/256.0f)
#define NSTEPS 256

__device__ __forceinline__ short f2bf(float f) {
    unsigned u = __float_as_uint(f);
    u = (u + 0x7fffu + ((u >> 16) & 1u)) >> 16;
    return (short)u;
}

__device__ __forceinline__ float fast_tanh(float x) {
    float e = __expf(2.f * x);
    return 1.f - __fdividef(2.f, e + 1.f);
}

// RELAXED agent-scope ops: reach the coherence point (IF) but emit NO cache
// invalidation/writeback instructions -> per-XCD L2 (W2p residency) untouched.
__device__ __forceinline__ float ld_agent_f(const float* p) {
    return __hip_atomic_load(p, __ATOMIC_RELAXED, __HIP_MEMORY_SCOPE_AGENT);
}
__device__ __forceinline__ void st_agent_f(float* p, float v) {
    __hip_atomic_store(p, v, __ATOMIC_RELAXED, __HIP_MEMORY_SCOPE_AGENT);
}
__device__ __forceinline__ unsigned long long ld_agent_u64(const void* p) {
    return __hip_atomic_load((const unsigned long long*)p, __ATOMIC_RELAXED, __HIP_MEMORY_SCOPE_AGENT);
}

// ---------------- weight permutation (A-fragment order, bf16) ----------------
__global__ void perm_w0(const float* __restrict__ W0, short* __restrict__ W0p) {
    int i = blockIdx.x * 256 + threadIdx.x;            // 32768 = 16ot*4kc*64*8
    int j = i & 7, l = (i >> 3) & 63, kc = (i >> 9) & 3, ot = i >> 11;
    int row = ot * 16 + (l & 15);
    int col = kc * 32 + ((l >> 4) << 3) + j;
    W0p[i] = f2bf(W0[row * 128 + col]);
}
__global__ void perm_w1(const float* __restrict__ W1, short* __restrict__ W1p) {
    int i = blockIdx.x * 256 + threadIdx.x;            // 131072 = 16ot*8kc*64*8
    int j = i & 7, l = (i >> 3) & 63, kc = (i >> 9) & 7, ot = i >> 12;
    int row = ot * 16 + (l & 15);
    int col = kc * 32 + ((l >> 4) << 3) + j;
    W1p[i] = f2bf(W1[row * 256 + col]);
}
// padded: 64 lv rows per h-tile (row 63 zeroed)
__global__ void perm_w2(const float* __restrict__ W2, short* __restrict__ W2p) {
    int i = blockIdx.x * 256 + threadIdx.x;            // 2097152 = 8ht*64lv*8kc*64*8
    int j = i & 7, ln = (i >> 3) & 63, kc = (i >> 9) & 7;
    int v = i >> 12;                                   // ht*64 + lv
    int ht = v >> 6, lv = v & 63;
    if (lv == 63) { W2p[i] = 0; return; }
    int row = (ht * 16 + (ln & 15)) * 63 + lv;         // W2 row = h*63 + l
    int col = kc * 32 + ((ln >> 4) << 3) + j;
    W2p[i] = f2bf(W2[row * 256 + col]);
}

// ---------------- ytmp[0] = x0 @ l1w^T + l1b ----------------
__global__ void y0_kernel(const float* __restrict__ x0, const float* __restrict__ l1w,
                          const float* __restrict__ l1b, float* __restrict__ y) {
    int i = blockIdx.x * 256 + threadIdx.x;            // 65536
    int b = i >> 7, h = i & 127;
    float s = l1b[h];
    #pragma unroll
    for (int d = 0; d < 8; ++d) s += x0[b * 8 + d] * l1w[h * 8 + d];
    y[i] = s;
}

// ---------------- persistent RK integrator ----------------
struct Smem {
    alignas(16) short ysb[16 * 136];
    alignas(16) short h1b[16 * 264];
    alignas(16) short h2b[16 * 264];
    float gsh[16 * 65];
    float b2sh[16 * 65];
    float b0sh[256];
    float b1sh[256];
    float kred[8][16][17];
};

// RK coefficients for building the NEXT stage's input from k1..k_s
__constant__ const float A2[1] = {0.161f};
__constant__ const float A3[2] = {-0.008480655492356989f, 0.335480655492357f};
__constant__ const float A4[3] = {2.8971530571054935f, -6.359448489975075f, 4.3622954328695815f};
__constant__ const float A5[4] = {5.325864828439257f, -11.748883564062828f, 7.4955393428898365f, -0.09249506636175525f};
__constant__ const float A6[5] = {5.86145544294642f, -12.92096931784711f, 8.159367898576159f, -0.071584973281401f, -0.028269050394068383f};

template<int STAGE>
__device__ __forceinline__ void do_stage(
    Smem& sm, int s, int gsi, int bg, int ht, int tid, int gi,
    float* __restrict__ ytmp,              // 2 x 65536 floats (double buffer)
    float* __restrict__ yfinal,
    const short* __restrict__ W0p, const short* __restrict__ W1p, const short* __restrict__ W2p,
    const float* __restrict__ logsig,
    unsigned* __restrict__ barctr,
    float& yreg, float (&kr)[5])
{
    const int w    = tid >> 6;
    const int lane = tid & 63;
    const int q    = lane >> 4;
    const int rr   = lane & 15;
    const float* ycur = ytmp + (gsi & 1) * 65536;
    float*       ynxt = ytmp + ((gsi + 1) & 1) * 65536;

    // ---------- barrier wait: all 8 ht-WGs of this bg finished stage gsi-1 ----------
    if (gsi > 0) {
        const unsigned target = 8u * (unsigned)gsi;
        while (__hip_atomic_load(&barctr[bg * 16], __ATOMIC_RELAXED, __HIP_MEMORY_SCOPE_AGENT) < target) { }
    }

    // ---------- phase 0: load stage-input vector -> ysb (bf16); g refresh at stage 2 ----------
    {
        const int r  = tid >> 5;            // 0..15
        const int c4 = (tid & 31) * 4;      // 0..124
        const float* yrow = ycur + (bg * 16 + r) * 128 + c4;
        unsigned long long u0 = ld_agent_u64(yrow);
        unsigned long long u1 = ld_agent_u64(yrow + 2);
        short4e sv;
        sv[0] = f2bf(__uint_as_float((unsigned)(u0 & 0xffffffffu)));
        sv[1] = f2bf(__uint_as_float((unsigned)(u0 >> 32)));
        sv[2] = f2bf(__uint_as_float((unsigned)(u1 & 0xffffffffu)));
        sv[3] = f2bf(__uint_as_float((unsigned)(u1 >> 32)));
        *reinterpret_cast<short4e*>(&sm.ysb[r * 136 + c4]) = sv;

        if constexpr (STAGE == 2) {         // refresh g for idx = s (stages 2..6 now, stage 1 next step)
            const int l0 = (tid & 31) * 2;
            const float* gp = logsig + (bg * 16 + r) * 16384 + s * 64 + 1;
            sm.gsh[r * 65 + l0]     = (l0 < 63)     ? gp[l0]     : 0.f;
            sm.gsh[r * 65 + l0 + 1] = (l0 + 1 < 63) ? gp[l0 + 1] : 0.f;
        }
    }
    __syncthreads();

    // ---------- phase 1: h1 = silu(W0 @ ys^T + b0) ----------
    #pragma unroll
    for (int oi = 0; oi < 2; ++oi) {
        int ot = w * 2 + oi;
        f32x4 acc0 = {0.f, 0.f, 0.f, 0.f}, acc1 = {0.f, 0.f, 0.f, 0.f};
        #pragma unroll
        for (int kc = 0; kc < 2; ++kc) {
            short8 af0 = *reinterpret_cast<const short8*>(W0p + (ot * 4 + kc) * 512 + lane * 8);
            short8 bf0 = *reinterpret_cast<const short8*>(&sm.ysb[rr * 136 + kc * 32 + q * 8]);
            acc0 = __builtin_amdgcn_mfma_f32_16x16x32_bf16(af0, bf0, acc0, 0, 0, 0);
            short8 af1 = *reinterpret_cast<const short8*>(W0p + (ot * 4 + kc + 2) * 512 + lane * 8);
            short8 bf1 = *reinterpret_cast<const short8*>(&sm.ysb[rr * 136 + (kc + 2) * 32 + q * 8]);
            acc1 = __builtin_amdgcn_mfma_f32_16x16x32_bf16(af1, bf1, acc1, 0, 0, 0);
        }
        int ob = ot * 16 + q * 4;
        float vv[4];
        #pragma unroll
        for (int jj = 0; jj < 4; ++jj) {
            float x = acc0[jj] + acc1[jj] + sm.b0sh[ob + jj];
            vv[jj] = x * __fdividef(1.f, 1.f + __expf(-x));
        }
        unsigned lo = (unsigned)(unsigned short)f2bf(vv[0]) | ((unsigned)(unsigned short)f2bf(vv[1]) << 16);
        unsigned hi = (unsigned)(unsigned short)f2bf(vv[2]) | ((unsigned)(unsigned short)f2bf(vv[3]) << 16);
        *reinterpret_cast<unsigned*>(&sm.h1b[rr * 264 + ob])     = lo;
        *reinterpret_cast<unsigned*>(&sm.h1b[rr * 264 + ob + 2]) = hi;
    }
    __syncthreads();

    // ---------- phase 2: h2 = silu(W1 @ h1^T + b1) ----------
    #pragma unroll
    for (int oi = 0; oi < 2; ++oi) {
        int ot = w * 2 + oi;
        f32x4 acc0 = {0.f, 0.f, 0.f, 0.f}, acc1 = {0.f, 0.f, 0.f, 0.f};
        #pragma unroll
        for (int kc = 0; kc < 4; ++kc) {
            short8 af0 = *reinterpret_cast<const short8*>(W1p + (ot * 8 + kc) * 512 + lane * 8);
            short8 bf0 = *reinterpret_cast<const short8*>(&sm.h1b[rr * 264 + kc * 32 + q * 8]);
            acc0 = __builtin_amdgcn_mfma_f32_16x16x32_bf16(af0, bf0, acc0, 0, 0, 0);
            short8 af1 = *reinterpret_cast<const short8*>(W1p + (ot * 8 + kc + 4) * 512 + lane * 8);
            short8 bf1 = *reinterpret_cast<const short8*>(&sm.h1b[rr * 264 + (kc + 4) * 32 + q * 8]);
            acc1 = __builtin_amdgcn_mfma_f32_16x16x32_bf16(af1, bf1, acc1, 0, 0, 0);
        }
        int ob = ot * 16 + q * 4;
        float vv[4];
        #pragma unroll
        for (int jj = 0; jj < 4; ++jj) {
            float x = acc0[jj] + acc1[jj] + sm.b1sh[ob + jj];
            vv[jj] = x * __fdividef(1.f, 1.f + __expf(-x));
        }
        unsigned lo = (unsigned)(unsigned short)f2bf(vv[0]) | ((unsigned)(unsigned short)f2bf(vv[1]) << 16);
        unsigned hi = (unsigned)(unsigned short)f2bf(vv[2]) | ((unsigned)(unsigned short)f2bf(vv[3]) << 16);
        *reinterpret_cast<unsigned*>(&sm.h2b[rr * 264 + ob])     = lo;
        *reinterpret_cast<unsigned*>(&sm.h2b[rr * 264 + ob + 2]) = hi;
    }
    __syncthreads();

    // ---------- phase 3: k_slice[b][h] = sum_l tanh(W2[h*63+l]·h2[b] + b2) * g[b][l] ----------
    float kacc[4] = {0.f, 0.f, 0.f, 0.f};
    const int lvbase = w * 8;
    #pragma unroll
    for (int i2 = 0; i2 < 4; ++i2) {
        const int lvA = lvbase + i2 * 2;
        const int lvB = lvA + 1;
        f32x4 aA0 = {0.f,0.f,0.f,0.f}, aA1 = {0.f,0.f,0.f,0.f};
        f32x4 aB0 = {0.f,0.f,0.f,0.f}, aB1 = {0.f,0.f,0.f,0.f};
        const short* wpA = W2p + (size_t)((ht * 64 + lvA) * 8) * 512 + lane * 8;
        const short* wpB = wpA + 8 * 512;
        #pragma unroll
        for (int kc = 0; kc < 4; ++kc) {
            short8 bf0 = *reinterpret_cast<const short8*>(&sm.h2b[rr * 264 + kc * 32 + q * 8]);
            short8 bf1 = *reinterpret_cast<const short8*>(&sm.h2b[rr * 264 + (kc + 4) * 32 + q * 8]);
            aA0 = __builtin_amdgcn_mfma_f32_16x16x32_bf16(*reinterpret_cast<const short8*>(wpA + kc * 512),       bf0, aA0, 0, 0, 0);
            aA1 = __builtin_amdgcn_mfma_f32_16x16x32_bf16(*reinterpret_cast<const short8*>(wpA + (kc + 4) * 512), bf1, aA1, 0, 0, 0);
            aB0 = __builtin_amdgcn_mfma_f32_16x16x32_bf16(*reinterpret_cast<const short8*>(wpB + kc * 512),       bf0, aB0, 0, 0, 0);
            aB1 = __builtin_amdgcn_mfma_f32_16x16x32_bf16(*reinterpret_cast<const short8*>(wpB + (kc + 4) * 512), bf1, aB1, 0, 0, 0);
        }
        float gA = sm.gsh[rr * 65 + lvA];
        float gB = sm.gsh[rr * 65 + lvB];
        #pragma unroll
        for (int jj = 0; jj < 4; ++jj) {
            float xA = aA0[jj] + aA1[jj] + sm.b2sh[(q * 4 + jj) * 65 + lvA];
            kacc[jj] += fast_tanh(xA) * gA;
            float xB = aB0[jj] + aB1[jj] + sm.b2sh[(q * 4 + jj) * 65 + lvB];
            kacc[jj] += fast_tanh(xB) * gB;
        }
    }
    #pragma unroll
    for (int jj = 0; jj < 4; ++jj) sm.kred[w][q * 4 + jj][rr] = kacc[jj];
    __syncthreads();

    // ---------- epilogue: reduce; update register k-history; publish next-stage input ----------
    if (tid < 256) {
        int bl = tid >> 4;
        int hl = tid & 15;
        float ssum = sm.kred[0][hl][bl] + sm.kred[1][hl][bl] + sm.kred[2][hl][bl] + sm.kred[3][hl][bl]
                   + sm.kred[4][hl][bl] + sm.kred[5][hl][bl] + sm.kred[6][hl][bl] + sm.kred[7][hl][bl];
        float nv;
        if constexpr (STAGE == 1) {
            kr[0] = ssum;
            nv = yreg + DT * (A2[0] * kr[0]);
        } else if constexpr (STAGE == 2) {
            kr[1] = ssum;
            nv = yreg + DT * (A3[0] * kr[0] + A3[1] * kr[1]);
        } else if constexpr (STAGE == 3) {
            kr[2] = ssum;
            nv = yreg + DT * (A4[0] * kr[0] + A4[1] * kr[1] + A4[2] * kr[2]);
        } else if constexpr (STAGE == 4) {
            kr[3] = ssum;
            nv = yreg + DT * (A5[0] * kr[0] + A5[1] * kr[1] + A5[2] * kr[2] + A5[3] * kr[3]);
        } else if constexpr (STAGE == 5) {
            kr[4] = ssum;
            nv = yreg + DT * (A6[0] * kr[0] + A6[1] * kr[1] + A6[2] * kr[2] + A6[3] * kr[3] + A6[4] * kr[4]);
        } else {
            nv = yreg + DT * (0.09646076681806523f * kr[0] + 0.01f * kr[1]
                 + 0.4798896504144996f * kr[2] + 1.379008574103742f * kr[3]
                 + (-3.290069515436081f) * kr[4] + 2.324710524099774f * ssum);
            yreg = nv;
            if (s == NSTEPS - 1) st_agent_f(&yfinal[gi], nv);
        }
        st_agent_f(&ynxt[gi], nv);
    }

    // ---------- barrier signal (syncthreads drains vmcnt -> stores at IF before the add) ----------
    __syncthreads();
    if (tid == 0) {
        __hip_atomic_fetch_add(&barctr[bg * 16], 1u, __ATOMIC_RELAXED, __HIP_MEMORY_SCOPE_AGENT);
    }
}

__global__ __launch_bounds__(512, 2) void rde_persistent(
    float* ytmp, float* yfinal, unsigned* barctr,
    const short* W0p, const short* W1p, const short* W2p,
    const float* b0, const float* b1, const float* b2,
    const float* logsig)
{
    __shared__ Smem sm;
    const int tid = threadIdx.x;
    const int bg  = blockIdx.x >> 3;
    const int ht  = blockIdx.x & 7;
    const int gi  = (bg * 16 + (tid >> 4)) * 128 + ht * 16 + (tid & 15);  // valid for tid<256

    // ---- one-time LDS init: biases + b2 slice + g(idx=0); register y slice ----
    if (tid < 256) sm.b0sh[tid] = b0[tid];
    else           sm.b1sh[tid - 256] = b1[tid - 256];
    {
        const int r  = tid >> 5;
        const int l0 = (tid & 31) * 2;
        const float* bp = b2 + (ht * 16 + r) * 63;
        sm.b2sh[r * 65 + l0]     = (l0 < 63)     ? bp[l0]     : 0.f;
        sm.b2sh[r * 65 + l0 + 1] = (l0 + 1 < 63) ? bp[l0 + 1] : 0.f;
        const float* gp = logsig + (bg * 16 + r) * 16384 + 0 * 64 + 1;
        sm.gsh[r * 65 + l0]      = (l0 < 63)     ? gp[l0]     : 0.f;
        sm.gsh[r * 65 + l0 + 1]  = (l0 + 1 < 63) ? gp[l0 + 1] : 0.f;
    }
    float yreg = 0.f;
    float kr[5] = {0.f, 0.f, 0.f, 0.f, 0.f};
    if (tid < 256) yreg = ld_agent_f(&ytmp[gi]);
    // (first __syncthreads inside do_stage<1> covers LDS init)

    #pragma unroll 1
    for (int s = 0; s < NSTEPS; ++s) {
        const int g6 = s * 6;
        do_stage<1>(sm, s, g6 + 0, bg, ht, tid, gi, ytmp, yfinal, W0p, W1p, W2p, logsig, barctr, yreg, kr);
        do_stage<2>(sm, s, g6 + 1, bg, ht, tid, gi, ytmp, yfinal, W0p, W1p, W2p, logsig, barctr, yreg, kr);
        do_stage<3>(sm, s, g6 + 2, bg, ht, tid, gi, ytmp, yfinal, W0p, W1p, W2p, logsig, barctr, yreg, kr);
        do_stage<4>(sm, s, g6 + 3, bg, ht, tid, gi, ytmp, yfinal, W0p, W1p, W2p, logsig, barctr, yreg, kr);
        do_stage<5>(sm, s, g6 + 4, bg, ht, tid, gi, ytmp, yfinal, W0p, W1p, W2p, logsig, barctr, yreg, kr);
        do_stage<6>(sm, s, g6 + 5, bg, ht, tid, gi, ytmp, yfinal, W0p, W1p, W2p, logsig, barctr, yreg, kr);
    }
}

// ---------------- final: softmax(yf @ l2w^T + l2b) ----------------
__global__ void out_kernel(const float* __restrict__ yf, const float* __restrict__ l2w,
                           const float* __restrict__ l2b, float* __restrict__ out) {
    int b = blockIdx.x, t = threadIdx.x;   // 64 threads
    float ya = yf[b * 128 + t], yb = yf[b * 128 + 64 + t];
    __shared__ float lg[10];
    for (int c = 0; c < 10; ++c) {
        float p = ya * l2w[c * 128 + t] + yb * l2w[c * 128 + 64 + t];
        for (int off = 32; off > 0; off >>= 1) p += __shfl_down(p, off);
        if (t == 0) lg[c] = p + l2b[c];
    }
    __syncthreads();
    if (t == 0) {
        float m = lg[0];
        for (int c = 1; c < 10; ++c) m = fmaxf(m, lg[c]);
        float s = 0.f, e[10];
        for (int c = 0; c < 10; ++c) { e[c] = expf(lg[c] - m); s += e[c]; }
        for (int c = 0; c < 10; ++c) out[b * 10 + c] = e[c] / s;
    }
}

extern "C" void kernel_launch(void* const* d_in, const int* in_sizes, int n_in,
                              void* d_out, int out_size, void* d_ws, size_t ws_size,
                              hipStream_t stream) {
    const float* logsig = (const float*)d_in[2];
    const float* x0  = (const float*)d_in[3];
    const float* W0  = (const float*)d_in[4];
    const float* b0  = (const float*)d_in[5];
    const float* W1  = (const float*)d_in[6];
    const float* b1  = (const float*)d_in[7];
    const float* W2  = (const float*)d_in[8];
    const float* b2  = (const float*)d_in[9];
    const float* l1w = (const float*)d_in[10];
    const float* l1b = (const float*)d_in[11];
    const float* l2w = (const float*)d_in[12];
    const float* l2b = (const float*)d_in[13];
    float* out = (float*)d_out;

    char* ws = (char*)d_ws;
    float*    ytmp   = (float*)(ws);                   // 2 x 512x128 f32 (double-buffered stage input)
    float*    yfinal = (float*)(ws + 524288);          // 512x128 f32
    short*    W0p    = (short*)(ws + 786432);          // 64 KB bf16
    short*    W1p    = (short*)(ws + 851968);          // 256 KB
    short*    W2p    = (short*)(ws + 1114112);         // 4 MB (padded 8*64*8*512)
    unsigned* barctr = (unsigned*)(ws + 5308416);      // 32 bg x 16 uints (64B padded)

    hipMemsetAsync(barctr, 0, 32 * 16 * sizeof(unsigned), stream);
    perm_w0<<<128, 256, 0, stream>>>(W0, W0p);
    perm_w1<<<512, 256, 0, stream>>>(W1, W1p);
    perm_w2<<<8192, 256, 0, stream>>>(W2, W2p);
    y0_kernel<<<256, 256, 0, stream>>>(x0, l1w, l1b, ytmp);   // slot 0 = stage-1 input of step 0

    void* args[] = {&ytmp, &yfinal, &barctr, &W0p, &W1p, &W2p, &b0, &b1, &b2, &logsig};
    hipLaunchCooperativeKernel((const void*)rde_persistent, dim3(256), dim3(512), args, 0, stream);

    out_kernel<<<512, 64, 0, stream>>>(yfinal, l2w, l2b, out);
}